// Round 10
// baseline (11625.997 us; speedup 1.0000x reference)
//
#include <hip/hip_runtime.h>
#include <hip/hip_bf16.h>

// Problem dims
#define BB 256
#define KK 512
#define UU 16
#define PP 64
#define HH 256
#define LL 64
#define THD 128   // 2*P
#define MB 16     // batch rows per group
#define NS 8      // unit-slices per group (32 GRU units each)
#define NG 16     // m-groups
#define NBLK (NG*NS)   // 128 blocks
#define NT 256

// LDS fragment regions (1 frag = 1KB = 512 f16; layout identical to R8 pack)
#define WHH_F 0     // 6 nt * 8 kk = 48
#define WIH_F 48    // 6 nt * 2 kk = 12
#define WHD_F 60    // 8 nt * 8 kk = 64
#define WLF_F 124   // 4 nt * 3 kk = 12
#define NFRG 136

#define FP2 104     // f_M pitch (f16)
#define XP2 72      // x_M pitch (f16)
#define TP2 132     // theta pitch (f32)

// h-exchange geometry (f16 elements)
#define HX_BUF 65536        // per-buffer: NG*MB*HH
#define HX_GRP 4096         // per-group: MB*HH

typedef _Float16 f16;
typedef _Float16 f16x8 __attribute__((ext_vector_type(8)));
typedef float f32x4 __attribute__((ext_vector_type(4)));

__device__ __forceinline__ float sigm(float x) { return 1.f / (1.f + __expf(-x)); }
__device__ __forceinline__ f32x4 MFMA(f16x8 a, f16x8 b, f32x4 c) {
  return __builtin_amdgcn_mfma_f32_16x16x32_f16(a, b, c, 0, 0, 0);
}

struct SM {
  alignas(16) f16 frg[NFRG * 512];       // 139264 B
  alignas(16) f16 x_M[MB * XP2];         // 2304
  alignas(16) f16 f_M[MB * FP2];         // 3328
  alignas(16) float th[MB * TP2];        // 8448
  alignas(16) float ubuf[2][MB][UU];     // 2048
  alignas(16) float jmp[UU * PP];        // 4096
  float dts[2][MB];                      // 128
  float bihs[96], bhhs[96];              // 768
  float bhead[THD];                      // 512
  float blift[LL];                       // 256
};                                       // total 161152 B

// stage one weight element into B-frag LDS layout (same k/n convention as R8)
__device__ __forceinline__ void put_frag(f16* frg, int base_f, int ntK, int nt,
                                         int n16, int k, float v) {
  int kk = k >> 5, lgp = (k >> 3) & 3, j = k & 7;
  int lane = lgp * 16 + n16;
  frg[(base_f + nt * ntK + kk) * 512 + lane * 8 + j] = (f16)v;
}

__device__ __forceinline__ void group_sync(unsigned* cnt, unsigned target, int t) {
  __threadfence();                 // release: wb dirty L2 (each thread's writes)
  __syncthreads();
  if (t == 0) {
    __hip_atomic_fetch_add(cnt, 1u, __ATOMIC_RELEASE, __HIP_MEMORY_SCOPE_AGENT);
    while (__hip_atomic_load(cnt, __ATOMIC_RELAXED, __HIP_MEMORY_SCOPE_AGENT) < target) {}
  }
  __syncthreads();
  __builtin_amdgcn_fence(__ATOMIC_ACQUIRE, "agent");   // inv stale L2 lines
}

#define FRG(FID) (*(const f16x8*)&sm.frg[(FID) * 512 + lane * 8])

__global__ __launch_bounds__(NT) void odernn_coop(
    const float* __restrict__ y0, const float* __restrict__ u_seq,
    const float* __restrict__ dt_seq, const float* __restrict__ W_lift,
    const float* __restrict__ b_lift, const float* __restrict__ W_ih,
    const float* __restrict__ b_ih, const float* __restrict__ W_hh,
    const float* __restrict__ b_hh, const float* __restrict__ W_head,
    const float* __restrict__ b_head, const float* __restrict__ jump,
    unsigned* __restrict__ ws_cnt, f16* __restrict__ hx,
    float* __restrict__ out_y, float* __restrict__ out_th) {
  __shared__ SM sm;
  const int t = threadIdx.x;
  const int lane = t & 63, wv = t >> 6, lm = lane & 15, lg = lane >> 4;
  const int bid = blockIdx.x, g = bid >> 3, ns = bid & 7;
  const int g16 = g * MB;
  const int ub = 32 * ns;          // first GRU unit of this block's slice

  // ---- stage weight slices into LDS B-frag layout ----
  for (int e = t; e < 96 * 256; e += NT) {         // W_hh slice: rows r32|z32|n32
    int l = e >> 8, k = e & 255;
    int gate = l >> 5, ul = l & 31;
    put_frag(sm.frg, WHH_F, 8, l >> 4, l & 15, k, W_hh[(gate * 256 + ub + ul) * 256 + k]);
  }
  for (int e = t; e < 96 * 64; e += NT) {          // W_ih slice
    int l = e >> 6, k = e & 63;
    int gate = l >> 5, ul = l & 31;
    put_frag(sm.frg, WIH_F, 2, l >> 4, l & 15, k, W_ih[(gate * 256 + ub + ul) * 64 + k]);
  }
  for (int e = t; e < 128 * 256; e += NT) {        // W_head FULL
    int l = e >> 8, k = e & 255;
    put_frag(sm.frg, WHD_F, 8, l >> 4, l & 15, k, W_head[l * 256 + k]);
  }
  for (int e = t; e < 64 * 96; e += NT) {          // W_lift FULL (K padded 80->96)
    int l = e / 96, k = e - l * 96;
    float v = (k < UU + PP) ? W_lift[l * 80 + k] : 0.f;
    put_frag(sm.frg, WLF_F, 3, l >> 4, l & 15, k, v);
  }
  // biases / jump
  if (t < 96) { int gate = t >> 5, ul = t & 31;
    sm.bihs[t] = b_ih[gate * 256 + ub + ul];
    sm.bhhs[t] = b_hh[gate * 256 + ub + ul]; }
  if (t < THD) sm.bhead[t] = b_head[t];
  if (t < LL)  sm.blift[t] = b_lift[t];
  for (int e = t; e < UU * PP; e += NT) sm.jmp[e] = jump[e];
  // f_M zero (covers pad), then u(0), y0
  for (int e = t; e < MB * FP2; e += NT) sm.f_M[e] = (f16)0.f;
  __syncthreads();
  if (t < 128) { int m = t >> 3, q = t & 7;
    float2 uv = *(const float2*)&u_seq[((size_t)(g16 + m) * KK) * UU + 2 * q];
    sm.ubuf[0][m][2 * q] = uv.x; sm.ubuf[0][m][2 * q + 1] = uv.y;
    sm.f_M[m * FP2 + 2 * q] = (f16)uv.x; sm.f_M[m * FP2 + 2 * q + 1] = (f16)uv.y; }
  if (t < MB) sm.dts[0][t] = dt_seq[(size_t)(g16 + t) * KK];
  const int rm = t >> 4, rp = (t & 15) * 4;
  float yr[4];
  { float4 yv = *(const float4*)&y0[(size_t)(g16 + rm) * PP + rp];
    yr[0] = yv.x; yr[1] = yv.y; yr[2] = yv.z; yr[3] = yv.w;
    sm.f_M[rm * FP2 + UU + rp]     = (f16)yv.x;
    sm.f_M[rm * FP2 + UU + rp + 1] = (f16)yv.y;
    sm.f_M[rm * FP2 + UU + rp + 2] = (f16)yv.z;
    sm.f_M[rm * FP2 + UU + rp + 3] = (f16)yv.w; }
  // zero h(-1) slice in buf 1
  { int m = t >> 4, c2 = (t & 15) * 2;
    hx[HX_BUF + g * HX_GRP + m * HH + ub + c2]     = (f16)0.f;
    hx[HX_BUF + g * HX_GRP + m * HH + ub + c2 + 1] = (f16)0.f; }
  // h-old registers for gate waves (thread owns (m=4lg+r, unit ub+16*wv+lm))
  float ho[4] = {0.f, 0.f, 0.f, 0.f};

  unsigned* cnt = ws_cnt + g * 16;
  group_sync(cnt, NS, t);          // h(-1) visible group-wide

#pragma unroll 1
  for (int j = 0; j < KK; ++j) {
    const int cb = j & 1;

    // ---- B: lift -> x (4 waves, n-tile wv) ----
    {
      const f16* fr = sm.f_M + lm * FP2 + lg * 8;
      f16x8 F0 = *(const f16x8*)(fr);
      f16x8 F1 = *(const f16x8*)(fr + 32);
      f16x8 F2 = *(const f16x8*)(fr + 64);
      f32x4 ax = {0.f, 0.f, 0.f, 0.f};
      ax = MFMA(F0, FRG(WLF_F + wv * 3 + 0), ax);
      ax = MFMA(F1, FRG(WLF_F + wv * 3 + 1), ax);
      ax = MFMA(F2, FRG(WLF_F + wv * 3 + 2), ax);
      const int c = wv * 16 + lm;
      const float bl = sm.blift[c];
#pragma unroll
      for (int r = 0; r < 4; ++r) {
        float v = ax[r] + bl;
        sm.x_M[(4 * lg + r) * XP2 + c] = (f16)(v * sigm(v));   // silu
      }
    }
    __syncthreads();

    // ---- C: gate slice (waves 0-1) ; u/dt prefetch (waves 2-3) ----
    if (wv < 2) {
      const f16* hb = hx + ((j + 1) & 1) * HX_BUF + g * HX_GRP + lm * HH + lg * 8;
      f16x8 H0 = *(const f16x8*)(hb);
      f16x8 H1 = *(const f16x8*)(hb + 32);
      f16x8 H2 = *(const f16x8*)(hb + 64);
      f16x8 H3 = *(const f16x8*)(hb + 96);
      f16x8 H4 = *(const f16x8*)(hb + 128);
      f16x8 H5 = *(const f16x8*)(hb + 160);
      f16x8 H6 = *(const f16x8*)(hb + 192);
      f16x8 H7 = *(const f16x8*)(hb + 224);
      const f16* xr = sm.x_M + lm * XP2 + lg * 8;
      f16x8 X0 = *(const f16x8*)(xr);
      f16x8 X1 = *(const f16x8*)(xr + 32);
      const int ntr = wv, ntz = 2 + wv, ntn = 4 + wv;
      f32x4 aR = {0.f,0.f,0.f,0.f}, aZ = aR, aI = aR, aH = aR;
      aR = MFMA(X0, FRG(WIH_F + ntr * 2 + 0), aR);
      aR = MFMA(X1, FRG(WIH_F + ntr * 2 + 1), aR);
      aR = MFMA(H0, FRG(WHH_F + ntr * 8 + 0), aR);
      aR = MFMA(H1, FRG(WHH_F + ntr * 8 + 1), aR);
      aR = MFMA(H2, FRG(WHH_F + ntr * 8 + 2), aR);
      aR = MFMA(H3, FRG(WHH_F + ntr * 8 + 3), aR);
      aR = MFMA(H4, FRG(WHH_F + ntr * 8 + 4), aR);
      aR = MFMA(H5, FRG(WHH_F + ntr * 8 + 5), aR);
      aR = MFMA(H6, FRG(WHH_F + ntr * 8 + 6), aR);
      aR = MFMA(H7, FRG(WHH_F + ntr * 8 + 7), aR);
      aZ = MFMA(X0, FRG(WIH_F + ntz * 2 + 0), aZ);
      aZ = MFMA(X1, FRG(WIH_F + ntz * 2 + 1), aZ);
      aZ = MFMA(H0, FRG(WHH_F + ntz * 8 + 0), aZ);
      aZ = MFMA(H1, FRG(WHH_F + ntz * 8 + 1), aZ);
      aZ = MFMA(H2, FRG(WHH_F + ntz * 8 + 2), aZ);
      aZ = MFMA(H3, FRG(WHH_F + ntz * 8 + 3), aZ);
      aZ = MFMA(H4, FRG(WHH_F + ntz * 8 + 4), aZ);
      aZ = MFMA(H5, FRG(WHH_F + ntz * 8 + 5), aZ);
      aZ = MFMA(H6, FRG(WHH_F + ntz * 8 + 6), aZ);
      aZ = MFMA(H7, FRG(WHH_F + ntz * 8 + 7), aZ);
      aI = MFMA(X0, FRG(WIH_F + ntn * 2 + 0), aI);
      aI = MFMA(X1, FRG(WIH_F + ntn * 2 + 1), aI);
      aH = MFMA(H0, FRG(WHH_F + ntn * 8 + 0), aH);
      aH = MFMA(H1, FRG(WHH_F + ntn * 8 + 1), aH);
      aH = MFMA(H2, FRG(WHH_F + ntn * 8 + 2), aH);
      aH = MFMA(H3, FRG(WHH_F + ntn * 8 + 3), aH);
      aH = MFMA(H4, FRG(WHH_F + ntn * 8 + 4), aH);
      aH = MFMA(H5, FRG(WHH_F + ntn * 8 + 5), aH);
      aH = MFMA(H6, FRG(WHH_F + ntn * 8 + 6), aH);
      aH = MFMA(H7, FRG(WHH_F + ntn * 8 + 7), aH);
      const int ul = 16 * wv + lm;
      const float br = sm.bihs[ul] + sm.bhhs[ul];
      const float bz = sm.bihs[32 + ul] + sm.bhhs[32 + ul];
      const float bi = sm.bihs[64 + ul];
      const float bh2 = sm.bhhs[64 + ul];
      f16* hw = hx + (j & 1) * HX_BUF + g * HX_GRP + ub + ul;
#pragma unroll
      for (int r = 0; r < 4; ++r) {
        float rr = sigm(aR[r] + br);
        float zz = sigm(aZ[r] + bz);
        float nn = 2.f * sigm(2.f * (aI[r] + bi + rr * (aH[r] + bh2))) - 1.f;  // tanh
        float hv = (1.f - zz) * nn + zz * ho[r];
        ho[r] = hv;
        hw[(4 * lg + r) * HH] = (f16)hv;
      }
    } else if (j + 1 < KK) {
      const int idx = t - 128;          // 0..127
      const int m = idx >> 3, q = idx & 7;
      float2 uv = *(const float2*)&u_seq[((size_t)(g16 + m) * KK + (j + 1)) * UU + 2 * q];
      sm.ubuf[cb ^ 1][m][2 * q] = uv.x; sm.ubuf[cb ^ 1][m][2 * q + 1] = uv.y;
      sm.f_M[m * FP2 + 2 * q] = (f16)uv.x; sm.f_M[m * FP2 + 2 * q + 1] = (f16)uv.y;
      if (idx < MB) sm.dts[cb ^ 1][idx] = dt_seq[(size_t)(g16 + idx) * KK + (j + 1)];
    }
    group_sync(cnt, (unsigned)(NS * (j + 2)), t);

    // ---- D: full head (redundant) -> theta; RK4 -> y; stores ----
    {
      const f16* hb2 = hx + (j & 1) * HX_BUF + g * HX_GRP + lm * HH + lg * 8;
      f16x8 G0 = *(const f16x8*)(hb2);
      f16x8 G1 = *(const f16x8*)(hb2 + 32);
      f16x8 G2 = *(const f16x8*)(hb2 + 64);
      f16x8 G3 = *(const f16x8*)(hb2 + 96);
      f16x8 G4 = *(const f16x8*)(hb2 + 128);
      f16x8 G5 = *(const f16x8*)(hb2 + 160);
      f16x8 G6 = *(const f16x8*)(hb2 + 192);
      f16x8 G7 = *(const f16x8*)(hb2 + 224);
      f32x4 t0 = {0.f,0.f,0.f,0.f}, t1 = t0;
      t0 = MFMA(G0, FRG(WHD_F + wv * 8 + 0), t0);
      t0 = MFMA(G1, FRG(WHD_F + wv * 8 + 1), t0);
      t0 = MFMA(G2, FRG(WHD_F + wv * 8 + 2), t0);
      t0 = MFMA(G3, FRG(WHD_F + wv * 8 + 3), t0);
      t0 = MFMA(G4, FRG(WHD_F + wv * 8 + 4), t0);
      t0 = MFMA(G5, FRG(WHD_F + wv * 8 + 5), t0);
      t0 = MFMA(G6, FRG(WHD_F + wv * 8 + 6), t0);
      t0 = MFMA(G7, FRG(WHD_F + wv * 8 + 7), t0);
      t1 = MFMA(G0, FRG(WHD_F + (wv + 4) * 8 + 0), t1);
      t1 = MFMA(G1, FRG(WHD_F + (wv + 4) * 8 + 1), t1);
      t1 = MFMA(G2, FRG(WHD_F + (wv + 4) * 8 + 2), t1);
      t1 = MFMA(G3, FRG(WHD_F + (wv + 4) * 8 + 3), t1);
      t1 = MFMA(G4, FRG(WHD_F + (wv + 4) * 8 + 4), t1);
      t1 = MFMA(G5, FRG(WHD_F + (wv + 4) * 8 + 5), t1);
      t1 = MFMA(G6, FRG(WHD_F + (wv + 4) * 8 + 6), t1);
      t1 = MFMA(G7, FRG(WHD_F + (wv + 4) * 8 + 7), t1);
      const float b0 = sm.bhead[wv * 16 + lm];
      const float b1 = sm.bhead[(wv + 4) * 16 + lm];
#pragma unroll
      for (int r = 0; r < 4; ++r) {
        sm.th[(4 * lg + r) * TP2 + wv * 16 + lm] = 0.001f + 1.999f * sigm(t0[r] + b0);
        sm.th[(4 * lg + r) * TP2 + (wv + 4) * 16 + lm] = 0.001f + 1.999f * sigm(t1[r] + b1);
      }
    }
    __syncthreads();
    {
      const float hdt = sm.dts[cb][rm];
      float4 outv;
#pragma unroll
      for (int i = 0; i < 4; ++i) {
        const int p = rp + i;
        float a = sm.th[rm * TP2 + p], dr = sm.th[rm * TP2 + 64 + p];
        float yv = yr[i];
#pragma unroll
        for (int uu = 0; uu < UU; ++uu)
          yv = fmaf(sm.ubuf[cb][rm][uu], sm.jmp[uu * PP + p], yv);
        float k1 = dr - a * yv;
        float k2 = dr - a * fmaf(0.5f * hdt, k1, yv);
        float k3 = dr - a * fmaf(0.5f * hdt, k2, yv);
        float k4 = dr - a * fmaf(hdt, k3, yv);
        yv = yv + (hdt * (1.f / 6.f)) * (k1 + 2.f * k2 + 2.f * k3 + k4);
        yv = fmaxf(yv, 0.f);
        yr[i] = yv;
        (&outv.x)[i] = yv;
        sm.f_M[rm * FP2 + UU + p] = (f16)yv;    // feat y-part for step j+1
      }
      if (ns == 0) {
        *(float4*)&out_y[((size_t)(g16 + rm) * KK + j) * PP + rp] = outv;
        const int c0 = (t & 15) * 8;
        *(float4*)&out_th[((size_t)(g16 + rm) * KK + j) * THD + c0] =
            *(const float4*)&sm.th[rm * TP2 + c0];
        *(float4*)&out_th[((size_t)(g16 + rm) * KK + j) * THD + c0 + 4] =
            *(const float4*)&sm.th[rm * TP2 + c0 + 4];
      }
    }
    __syncthreads();
  }
}

extern "C" void kernel_launch(void* const* d_in, const int* in_sizes, int n_in,
                              void* d_out, int out_size, void* d_ws, size_t ws_size,
                              hipStream_t stream) {
  (void)in_sizes; (void)n_in; (void)out_size; (void)ws_size;
  const float* y0     = (const float*)d_in[0];
  const float* u_seq  = (const float*)d_in[1];
  const float* dt_seq = (const float*)d_in[2];
  const float* W_lift = (const float*)d_in[3];
  const float* b_lift = (const float*)d_in[4];
  const float* W_ih   = (const float*)d_in[5];
  const float* b_ih   = (const float*)d_in[6];
  const float* W_hh   = (const float*)d_in[7];
  const float* b_hh   = (const float*)d_in[8];
  const float* W_head = (const float*)d_in[9];
  const float* b_head = (const float*)d_in[10];
  const float* jump   = (const float*)d_in[11];
  float* outy = (float*)d_out;
  float* outt = outy + (size_t)BB * KK * PP;
  unsigned* cnt = (unsigned*)d_ws;
  f16* hx = (f16*)((char*)d_ws + 1024);

  hipMemsetAsync(d_ws, 0, 1024, stream);   // reset barrier counters (captured node)
  void* args[] = {
    (void*)&y0, (void*)&u_seq, (void*)&dt_seq, (void*)&W_lift, (void*)&b_lift,
    (void*)&W_ih, (void*)&b_ih, (void*)&W_hh, (void*)&b_hh, (void*)&W_head,
    (void*)&b_head, (void*)&jump, (void*)&cnt, (void*)&hx, (void*)&outy, (void*)&outt
  };
  hipLaunchCooperativeKernel((const void*)odernn_coop, dim3(NBLK), dim3(NT),
                             args, 0, stream);
}

// Round 11
// 3110.923 us; speedup vs baseline: 3.7372x; 3.7372x over previous
//
#include <hip/hip_runtime.h>
#include <hip/hip_bf16.h>

// Problem dims
#define BB 256
#define KK 512
#define UU 16
#define PP 64
#define HH 256
#define LL 64
#define THD 128   // 2*P
#define MB 16     // batch rows per group
#define NS 8      // unit-slices per group (32 GRU units each)
#define NG 16     // m-groups
#define NBLK (NG*NS)   // 128 blocks
#define NT 256

// LDS fragment regions (1 frag = 1KB = 512 f16; layout identical to R8/R10 pack)
#define WHH_F 0     // 6 nt * 8 kk = 48
#define WIH_F 48    // 6 nt * 2 kk = 12
#define WHD_F 60    // 8 nt * 8 kk = 64
#define WLF_F 124   // 4 nt * 3 kk = 12
#define NFRG 136

#define FP2 104     // f_M pitch (f16)
#define XP2 72      // x_M pitch (f16)
#define TP2 132     // theta pitch (f32)

// h-exchange geometry (f16 elements)
#define HX_BUF 65536        // per-buffer: NG*MB*HH
#define HX_GRP 4096         // per-group: MB*HH

typedef _Float16 f16;
typedef _Float16 f16x8 __attribute__((ext_vector_type(8)));
typedef float f32x4 __attribute__((ext_vector_type(4)));

__device__ __forceinline__ float sigm(float x) { return 1.f / (1.f + __expf(-x)); }
__device__ __forceinline__ f32x4 MFMA(f16x8 a, f16x8 b, f32x4 c) {
  return __builtin_amdgcn_mfma_f32_16x16x32_f16(a, b, c, 0, 0, 0);
}

// device-coherent (MALL-level) access, bypassing L1+L2: sc0 sc1 flags.
// No cache-wide fences needed: these lines never live in L1/L2.
#define GLD16(dst, p) \
  asm volatile("global_load_dwordx4 %0, %1, off sc0 sc1" : "=&v"(dst) : "v"(p))
#define GSTH(p, v) \
  asm volatile("global_store_short %0, %1, off sc0 sc1" :: "v"(p), "v"(v) : "memory")
#define VM0() do { asm volatile("s_waitcnt vmcnt(0)" ::: "memory"); \
                   __builtin_amdgcn_sched_barrier(0); } while (0)

struct SM {
  alignas(16) f16 frg[NFRG * 512];       // 139264 B
  alignas(16) f16 x_M[MB * XP2];         // 2304
  alignas(16) f16 f_M[MB * FP2];         // 3328
  alignas(16) float th[MB * TP2];        // 8448
  alignas(16) float ubuf[2][MB][UU];     // 2048
  alignas(16) float jmp[UU * PP];        // 4096
  float dts[2][MB];                      // 128
  float bihs[96], bhhs[96];              // 768
  float bhead[THD];                      // 512
  float blift[LL];                       // 256
};                                       // total 161152 B

// stage one weight element into B-frag LDS layout (same k/n convention as R8)
__device__ __forceinline__ void put_frag(f16* frg, int base_f, int ntK, int nt,
                                         int n16, int k, float v) {
  int kk = k >> 5, lgp = (k >> 3) & 3, j = k & 7;
  int lane = lgp * 16 + n16;
  frg[(base_f + nt * ntK + kk) * 512 + lane * 8 + j] = (f16)v;
}

#define FRG(FID) (*(const f16x8*)&sm.frg[(FID) * 512 + lane * 8])

__global__ __launch_bounds__(NT) void odernn_coop(
    const float* __restrict__ y0, const float* __restrict__ u_seq,
    const float* __restrict__ dt_seq, const float* __restrict__ W_lift,
    const float* __restrict__ b_lift, const float* __restrict__ W_ih,
    const float* __restrict__ b_ih, const float* __restrict__ W_hh,
    const float* __restrict__ b_hh, const float* __restrict__ W_head,
    const float* __restrict__ b_head, const float* __restrict__ jump,
    unsigned* __restrict__ ws_cnt, f16* __restrict__ hx,
    float* __restrict__ out_y, float* __restrict__ out_th) {
  __shared__ SM sm;
  const int t = threadIdx.x;
  const int lane = t & 63, wv = t >> 6, lm = lane & 15, lg = lane >> 4;
  const int bid = blockIdx.x, g = bid >> 3, ns = bid & 7;
  const int g16 = g * MB;
  const int ub = 32 * ns;          // first GRU unit of this block's slice

  // ---- stage weight slices into LDS B-frag layout (verified R10) ----
  for (int e = t; e < 96 * 256; e += NT) {         // W_hh slice: rows r32|z32|n32
    int l = e >> 8, k = e & 255;
    int gate = l >> 5, ul = l & 31;
    put_frag(sm.frg, WHH_F, 8, l >> 4, l & 15, k, W_hh[(gate * 256 + ub + ul) * 256 + k]);
  }
  for (int e = t; e < 96 * 64; e += NT) {          // W_ih slice
    int l = e >> 6, k = e & 63;
    int gate = l >> 5, ul = l & 31;
    put_frag(sm.frg, WIH_F, 2, l >> 4, l & 15, k, W_ih[(gate * 256 + ub + ul) * 64 + k]);
  }
  for (int e = t; e < 128 * 256; e += NT) {        // W_head FULL
    int l = e >> 8, k = e & 255;
    put_frag(sm.frg, WHD_F, 8, l >> 4, l & 15, k, W_head[l * 256 + k]);
  }
  for (int e = t; e < 64 * 96; e += NT) {          // W_lift FULL (K padded 80->96)
    int l = e / 96, k = e - l * 96;
    float v = (k < UU + PP) ? W_lift[l * 80 + k] : 0.f;
    put_frag(sm.frg, WLF_F, 3, l >> 4, l & 15, k, v);
  }
  if (t < 96) { int gate = t >> 5, ul = t & 31;
    sm.bihs[t] = b_ih[gate * 256 + ub + ul];
    sm.bhhs[t] = b_hh[gate * 256 + ub + ul]; }
  if (t < THD) sm.bhead[t] = b_head[t];
  if (t < LL)  sm.blift[t] = b_lift[t];
  for (int e = t; e < UU * PP; e += NT) sm.jmp[e] = jump[e];
  for (int e = t; e < MB * FP2; e += NT) sm.f_M[e] = (f16)0.f;
  __syncthreads();
  if (t < 128) { int m = t >> 3, q = t & 7;
    float2 uv = *(const float2*)&u_seq[((size_t)(g16 + m) * KK) * UU + 2 * q];
    sm.ubuf[0][m][2 * q] = uv.x; sm.ubuf[0][m][2 * q + 1] = uv.y;
    sm.f_M[m * FP2 + 2 * q] = (f16)uv.x; sm.f_M[m * FP2 + 2 * q + 1] = (f16)uv.y; }
  if (t < MB) sm.dts[0][t] = dt_seq[(size_t)(g16 + t) * KK];
  const int rm = t >> 4, rp = (t & 15) * 4;
  float yr[4];
  { float4 yv = *(const float4*)&y0[(size_t)(g16 + rm) * PP + rp];
    yr[0] = yv.x; yr[1] = yv.y; yr[2] = yv.z; yr[3] = yv.w;
    sm.f_M[rm * FP2 + UU + rp]     = (f16)yv.x;
    sm.f_M[rm * FP2 + UU + rp + 1] = (f16)yv.y;
    sm.f_M[rm * FP2 + UU + rp + 2] = (f16)yv.z;
    sm.f_M[rm * FP2 + UU + rp + 3] = (f16)yv.w; }
  float ho[4] = {0.f, 0.f, 0.f, 0.f};
  // h A-fragments (loaded in D each step, reused as gate A next step); h(-1)=0
  f16x8 G0 = {}, G1 = {}, G2 = {}, G3 = {}, G4 = {}, G5 = {}, G6 = {}, G7 = {};

  unsigned* cnt = ws_cnt + g * 16;   // 64B-separated per-group counter
  __syncthreads();

#pragma unroll 1
  for (int j = 0; j < KK; ++j) {
    const int cb = j & 1;

    // ---- B: lift -> x (all 4 waves, n-tile wv) ----
    {
      const f16* fr = sm.f_M + lm * FP2 + lg * 8;
      f16x8 F0 = *(const f16x8*)(fr);
      f16x8 F1 = *(const f16x8*)(fr + 32);
      f16x8 F2 = *(const f16x8*)(fr + 64);
      f32x4 ax = {0.f, 0.f, 0.f, 0.f};
      ax = MFMA(F0, FRG(WLF_F + wv * 3 + 0), ax);
      ax = MFMA(F1, FRG(WLF_F + wv * 3 + 1), ax);
      ax = MFMA(F2, FRG(WLF_F + wv * 3 + 2), ax);
      const int c = wv * 16 + lm;
      const float bl = sm.blift[c];
#pragma unroll
      for (int r = 0; r < 4; ++r) {
        float v = ax[r] + bl;
        sm.x_M[(4 * lg + r) * XP2 + c] = (f16)(v * sigm(v));   // silu
      }
    }
    __syncthreads();

    // ---- C: gate slice (waves 0-1, h = G regs) ; u/dt prefetch (waves 2-3) ----
    if (wv < 2) {
      const f16* xr = sm.x_M + lm * XP2 + lg * 8;
      f16x8 X0 = *(const f16x8*)(xr);
      f16x8 X1 = *(const f16x8*)(xr + 32);
      const int ntr = wv, ntz = 2 + wv, ntn = 4 + wv;
      f32x4 aR = {0.f,0.f,0.f,0.f}, aZ = aR, aI = aR, aH = aR;
      aR = MFMA(X0, FRG(WIH_F + ntr * 2 + 0), aR);
      aR = MFMA(X1, FRG(WIH_F + ntr * 2 + 1), aR);
      aR = MFMA(G0, FRG(WHH_F + ntr * 8 + 0), aR);
      aR = MFMA(G1, FRG(WHH_F + ntr * 8 + 1), aR);
      aR = MFMA(G2, FRG(WHH_F + ntr * 8 + 2), aR);
      aR = MFMA(G3, FRG(WHH_F + ntr * 8 + 3), aR);
      aR = MFMA(G4, FRG(WHH_F + ntr * 8 + 4), aR);
      aR = MFMA(G5, FRG(WHH_F + ntr * 8 + 5), aR);
      aR = MFMA(G6, FRG(WHH_F + ntr * 8 + 6), aR);
      aR = MFMA(G7, FRG(WHH_F + ntr * 8 + 7), aR);
      aZ = MFMA(X0, FRG(WIH_F + ntz * 2 + 0), aZ);
      aZ = MFMA(X1, FRG(WIH_F + ntz * 2 + 1), aZ);
      aZ = MFMA(G0, FRG(WHH_F + ntz * 8 + 0), aZ);
      aZ = MFMA(G1, FRG(WHH_F + ntz * 8 + 1), aZ);
      aZ = MFMA(G2, FRG(WHH_F + ntz * 8 + 2), aZ);
      aZ = MFMA(G3, FRG(WHH_F + ntz * 8 + 3), aZ);
      aZ = MFMA(G4, FRG(WHH_F + ntz * 8 + 4), aZ);
      aZ = MFMA(G5, FRG(WHH_F + ntz * 8 + 5), aZ);
      aZ = MFMA(G6, FRG(WHH_F + ntz * 8 + 6), aZ);
      aZ = MFMA(G7, FRG(WHH_F + ntz * 8 + 7), aZ);
      aI = MFMA(X0, FRG(WIH_F + ntn * 2 + 0), aI);
      aI = MFMA(X1, FRG(WIH_F + ntn * 2 + 1), aI);
      aH = MFMA(G0, FRG(WHH_F + ntn * 8 + 0), aH);
      aH = MFMA(G1, FRG(WHH_F + ntn * 8 + 1), aH);
      aH = MFMA(G2, FRG(WHH_F + ntn * 8 + 2), aH);
      aH = MFMA(G3, FRG(WHH_F + ntn * 8 + 3), aH);
      aH = MFMA(G4, FRG(WHH_F + ntn * 8 + 4), aH);
      aH = MFMA(G5, FRG(WHH_F + ntn * 8 + 5), aH);
      aH = MFMA(G6, FRG(WHH_F + ntn * 8 + 6), aH);
      aH = MFMA(G7, FRG(WHH_F + ntn * 8 + 7), aH);
      const int ul = 16 * wv + lm;
      const float br = sm.bihs[ul] + sm.bhhs[ul];
      const float bz = sm.bihs[32 + ul] + sm.bhhs[32 + ul];
      const float bi = sm.bihs[64 + ul];
      const float bh2 = sm.bhhs[64 + ul];
      f16* hw = hx + cb * HX_BUF + g * HX_GRP + ub + ul;
#pragma unroll
      for (int r = 0; r < 4; ++r) {
        float rr = sigm(aR[r] + br);
        float zz = sigm(aZ[r] + bz);
        float nn = 2.f * sigm(2.f * (aI[r] + bi + rr * (aH[r] + bh2))) - 1.f;  // tanh
        float hv = (1.f - zz) * nn + zz * ho[r];
        ho[r] = hv;
        f16 h16 = (f16)hv;
        unsigned hv32 = (unsigned)__builtin_bit_cast(unsigned short, h16);
        GSTH(hw + (4 * lg + r) * HH, hv32);
      }
      asm volatile("s_waitcnt vmcnt(0)" ::: "memory");   // stores at MALL
      if (lane == 0) atomicAdd(cnt, 1u);                 // device-scope (m20)
    } else if (j + 1 < KK) {
      const int idx = t - 128;          // 0..127
      const int m = idx >> 3, q = idx & 7;
      float2 uv = *(const float2*)&u_seq[((size_t)(g16 + m) * KK + (j + 1)) * UU + 2 * q];
      sm.ubuf[cb ^ 1][m][2 * q] = uv.x; sm.ubuf[cb ^ 1][m][2 * q + 1] = uv.y;
      sm.f_M[m * FP2 + 2 * q] = (f16)uv.x; sm.f_M[m * FP2 + 2 * q + 1] = (f16)uv.y;
      if (idx < MB) sm.dts[cb ^ 1][idx] = dt_seq[(size_t)(g16 + idx) * KK + (j + 1)];
    }
    // ---- group-ready poll (no fences; counter at coherence point) ----
    if (t == 128) {
      const unsigned tgt = 16u * (unsigned)(j + 1);
      int guard = 200000;
      while (__hip_atomic_load(cnt, __ATOMIC_RELAXED, __HIP_MEMORY_SCOPE_AGENT) < tgt
             && --guard) {}
    }
    __syncthreads();

    // ---- D: load h(j) (sc0sc1, fresh from MALL) -> head -> theta ----
    {
      const f16* hb2 = hx + cb * HX_BUF + g * HX_GRP + lm * HH + lg * 8;
      GLD16(G0, hb2);        GLD16(G1, hb2 + 32);
      GLD16(G2, hb2 + 64);   GLD16(G3, hb2 + 96);
      GLD16(G4, hb2 + 128);  GLD16(G5, hb2 + 160);
      GLD16(G6, hb2 + 192);  GLD16(G7, hb2 + 224);
      VM0();
      f32x4 acc0 = {0.f,0.f,0.f,0.f}, acc1 = acc0;
      acc0 = MFMA(G0, FRG(WHD_F + wv * 8 + 0), acc0);
      acc0 = MFMA(G1, FRG(WHD_F + wv * 8 + 1), acc0);
      acc0 = MFMA(G2, FRG(WHD_F + wv * 8 + 2), acc0);
      acc0 = MFMA(G3, FRG(WHD_F + wv * 8 + 3), acc0);
      acc0 = MFMA(G4, FRG(WHD_F + wv * 8 + 4), acc0);
      acc0 = MFMA(G5, FRG(WHD_F + wv * 8 + 5), acc0);
      acc0 = MFMA(G6, FRG(WHD_F + wv * 8 + 6), acc0);
      acc0 = MFMA(G7, FRG(WHD_F + wv * 8 + 7), acc0);
      acc1 = MFMA(G0, FRG(WHD_F + (wv + 4) * 8 + 0), acc1);
      acc1 = MFMA(G1, FRG(WHD_F + (wv + 4) * 8 + 1), acc1);
      acc1 = MFMA(G2, FRG(WHD_F + (wv + 4) * 8 + 2), acc1);
      acc1 = MFMA(G3, FRG(WHD_F + (wv + 4) * 8 + 3), acc1);
      acc1 = MFMA(G4, FRG(WHD_F + (wv + 4) * 8 + 4), acc1);
      acc1 = MFMA(G5, FRG(WHD_F + (wv + 4) * 8 + 5), acc1);
      acc1 = MFMA(G6, FRG(WHD_F + (wv + 4) * 8 + 6), acc1);
      acc1 = MFMA(G7, FRG(WHD_F + (wv + 4) * 8 + 7), acc1);
      const float b0 = sm.bhead[wv * 16 + lm];
      const float b1 = sm.bhead[(wv + 4) * 16 + lm];
#pragma unroll
      for (int r = 0; r < 4; ++r) {
        sm.th[(4 * lg + r) * TP2 + wv * 16 + lm] = 0.001f + 1.999f * sigm(acc0[r] + b0);
        sm.th[(4 * lg + r) * TP2 + (wv + 4) * 16 + lm] = 0.001f + 1.999f * sigm(acc1[r] + b1);
      }
    }
    __syncthreads();

    // ---- F: jump + RK4 + clamp + stores + feat y-part ----
    {
      const float hdt = sm.dts[cb][rm];
      float4 outv;
#pragma unroll
      for (int i = 0; i < 4; ++i) {
        const int p = rp + i;
        float a = sm.th[rm * TP2 + p], dr = sm.th[rm * TP2 + 64 + p];
        float yv = yr[i];
#pragma unroll
        for (int uu = 0; uu < UU; ++uu)
          yv = fmaf(sm.ubuf[cb][rm][uu], sm.jmp[uu * PP + p], yv);
        float k1 = dr - a * yv;
        float k2 = dr - a * fmaf(0.5f * hdt, k1, yv);
        float k3 = dr - a * fmaf(0.5f * hdt, k2, yv);
        float k4 = dr - a * fmaf(hdt, k3, yv);
        yv = yv + (hdt * (1.f / 6.f)) * (k1 + 2.f * k2 + 2.f * k3 + k4);
        yv = fmaxf(yv, 0.f);
        yr[i] = yv;
        (&outv.x)[i] = yv;
        sm.f_M[rm * FP2 + UU + p] = (f16)yv;    // feat y-part for step j+1
      }
      if (ns == 0) {
        *(float4*)&out_y[((size_t)(g16 + rm) * KK + j) * PP + rp] = outv;
        const int c0 = (t & 15) * 8;
        *(float4*)&out_th[((size_t)(g16 + rm) * KK + j) * THD + c0] =
            *(const float4*)&sm.th[rm * TP2 + c0];
        *(float4*)&out_th[((size_t)(g16 + rm) * KK + j) * THD + c0 + 4] =
            *(const float4*)&sm.th[rm * TP2 + c0 + 4];
      }
    }
    __syncthreads();
  }
}

extern "C" void kernel_launch(void* const* d_in, const int* in_sizes, int n_in,
                              void* d_out, int out_size, void* d_ws, size_t ws_size,
                              hipStream_t stream) {
  (void)in_sizes; (void)n_in; (void)out_size; (void)ws_size;
  const float* y0     = (const float*)d_in[0];
  const float* u_seq  = (const float*)d_in[1];
  const float* dt_seq = (const float*)d_in[2];
  const float* W_lift = (const float*)d_in[3];
  const float* b_lift = (const float*)d_in[4];
  const float* W_ih   = (const float*)d_in[5];
  const float* b_ih   = (const float*)d_in[6];
  const float* W_hh   = (const float*)d_in[7];
  const float* b_hh   = (const float*)d_in[8];
  const float* W_head = (const float*)d_in[9];
  const float* b_head = (const float*)d_in[10];
  const float* jump   = (const float*)d_in[11];
  float* outy = (float*)d_out;
  float* outt = outy + (size_t)BB * KK * PP;
  unsigned* cnt = (unsigned*)d_ws;
  f16* hx = (f16*)((char*)d_ws + 1024);

  hipMemsetAsync(d_ws, 0, 1024, stream);   // reset group counters (captured node)
  void* args[] = {
    (void*)&y0, (void*)&u_seq, (void*)&dt_seq, (void*)&W_lift, (void*)&b_lift,
    (void*)&W_ih, (void*)&b_ih, (void*)&W_hh, (void*)&b_hh, (void*)&W_head,
    (void*)&b_head, (void*)&jump, (void*)&cnt, (void*)&hx, (void*)&outy, (void*)&outt
  };
  hipLaunchCooperativeKernel((const void*)odernn_coop, dim3(NBLK), dim3(NT),
                             args, 0, stream);
}